// Round 6
// baseline (544.420 us; speedup 1.0000x reference)
//
#include <hip/hip_runtime.h>
#include <hip/hip_bf16.h>
#include <hip/hip_fp16.h>

// Problem constants
#define TB 128
#define TT 500
#define TS 200
#define TE 100
#define TH 100
#define NCLS 400              // 2*S  (one-hot width of x)
#define NG   400              // 4*H  (gate width)
#define BT   (TB*TT)          // 64000 (b,t) pairs
#define BLK  896              // 14 waves: 0-12 dot (800 active), 13 scan

typedef _Float16 h2_t __attribute__((ext_vector_type(2)));
union U16 { float4 f4; h2_t h[4]; };

__device__ __forceinline__ float fsig(float x) { return 1.0f / (1.0f + __expf(-x)); }
__device__ __forceinline__ float ftanh(float x) { float e = __expf(2.0f * x); return 1.0f - 2.0f / (e + 1.0f); }

__device__ __forceinline__ float FDOT2(h2_t a, h2_t b, float c) {
#if __has_builtin(__builtin_amdgcn_fdot2)
  return __builtin_amdgcn_fdot2(a, b, c, false);
#else
  return c + (float)a.x * (float)b.x + (float)a.y * (float)b.y;
#endif
}

// 56-half dot: 7 float4 of packed f16 weights against 7 float4 of packed h
__device__ __forceinline__ float dot56(const float4* hp, int hb,
                                       const float4& w0, const float4& w1,
                                       const float4& w2, const float4& w3,
                                       const float4& w4, const float4& w5,
                                       const float4& w6) {
  float a0 = 0.0f, a1 = 0.0f;
  #define DOTC(c, wr) { U16 uh, uw; uh.f4 = hp[hb + c]; uw.f4 = wr; \
    a0 = FDOT2(uh.h[0], uw.h[0], a0); a1 = FDOT2(uh.h[1], uw.h[1], a1); \
    a0 = FDOT2(uh.h[2], uw.h[2], a0); a1 = FDOT2(uh.h[3], uw.h[3], a1); }
  DOTC(0, w0) DOTC(1, w1) DOTC(2, w2) DOTC(3, w3)
  DOTC(4, w4) DOTC(5, w5) DOTC(6, w6)
  #undef DOTC
  return a0 + a1;
}

// ---------------------------------------------------------------------------
// Kernel A: compress one-hot x (B,T,400) -> idx2 and q (B,T,200) -> qi.
// One wave per (b,t).
// ---------------------------------------------------------------------------
__global__ void k_compress(const float* __restrict__ x, const float* __restrict__ q,
                           int* __restrict__ idx2, int* __restrict__ qi) {
  int gid  = blockIdx.x * blockDim.x + threadIdx.x;
  int wave = gid >> 6;
  int lane = threadIdx.x & 63;
  if (wave >= BT) return;

  const float4* xr = (const float4*)(x + (size_t)wave * NCLS);
  int li = -1;
  {
    float4 v = xr[lane];
    if (v.x > 0.5f) li = lane * 4 + 0;
    if (v.y > 0.5f) li = lane * 4 + 1;
    if (v.z > 0.5f) li = lane * 4 + 2;
    if (v.w > 0.5f) li = lane * 4 + 3;
    int ci = 64 + lane;
    if (ci < 100) {
      float4 w = xr[ci];
      if (w.x > 0.5f) li = ci * 4 + 0;
      if (w.y > 0.5f) li = ci * 4 + 1;
      if (w.z > 0.5f) li = ci * 4 + 2;
      if (w.w > 0.5f) li = ci * 4 + 3;
    }
  }
  #pragma unroll
  for (int off = 32; off; off >>= 1) li = max(li, __shfl_xor(li, off));

  const float4* qr = (const float4*)(q + (size_t)wave * TS);
  int qj = -1;
  if (lane < 50) {
    float4 v = qr[lane];
    if (v.x > 0.5f) qj = lane * 4 + 0;
    if (v.y > 0.5f) qj = lane * 4 + 1;
    if (v.z > 0.5f) qj = lane * 4 + 2;
    if (v.w > 0.5f) qj = lane * 4 + 3;
  }
  #pragma unroll
  for (int off = 32; off; off >>= 1) qj = max(qj, __shfl_xor(qj, off));

  if (lane == 0) { idx2[wave] = li; qi[wave] = qj; }
}

// ---------------------------------------------------------------------------
// Kernel B: precompute G, base, count rows, Wo^T, and packed-f16 R columns.
// Rh2[j*56 + m] = half2( R[2m][j], R[2m+1][j] ), zero-padded for k >= 100.
// Column stride = 56 half2 = 112 halves = 14 float4.
// ---------------------------------------------------------------------------
__global__ void k_precompute(const float* __restrict__ Wx, const float* __restrict__ bx,
                             const float* __restrict__ K, const float* __restrict__ lb,
                             const float* __restrict__ Wo, const float* __restrict__ R,
                             float* __restrict__ G, float* __restrict__ base,
                             float* __restrict__ crow0, float* __restrict__ crow1,
                             float* __restrict__ WoT, __half2* __restrict__ Rh2) {
  int bid = blockIdx.x, tid = threadIdx.x;
  if (bid < NCLS) {
    if (tid < NG) {
      float acc = 0.0f;
      for (int e = 0; e < TE; ++e) acc = fmaf(Wx[bid * TE + e], K[e * NG + tid], acc);
      G[bid * NG + tid] = acc;
    }
  } else if (bid == NCLS) {
    if (tid < NG) {
      float acc = lb[tid];
      for (int e = 0; e < TE; ++e) acc = fmaf(bx[e], K[e * NG + tid], acc);
      base[tid]  = acc;
      crow0[tid] = K[100 * NG + tid] + K[102 * NG + tid];
      crow1[tid] = K[101 * NG + tid] + K[102 * NG + tid];
    }
  } else {
    int id = (bid - NCLS - 1) * 512 + tid;
    if (id < TS * TH) {
      int s = id / TH, k = id % TH;
      WoT[id] = Wo[k * TS + s];
    } else {
      int id2 = id - TS * TH;
      if (id2 < NG * 56) {
        int j = id2 / 56, m = id2 % 56;
        int k0 = 2 * m, k1 = 2 * m + 1;
        float a = (k0 < TH) ? R[k0 * NG + j] : 0.0f;
        float b = (k1 < TH) ? R[k1 * NG + j] : 0.0f;
        Rh2[id2] = __halves2half2(__float2half_rn(a), __float2half_rn(b));
      }
    }
  }
}

// ---------------------------------------------------------------------------
// Kernel C: LSTM recurrence, single-barrier step. One block per batch b.
// Thread tid = 8u + 2*gt + p (tid<800): unit u, gate gt, half-column p.
// Each holds 7 float4 (28 VGPRs) of packed-f16 weights for halves
// [p*56, p*56+56) of gate-column j = gt*100 + u (round-5-proven profile).
// Per step: ONE __syncthreads; h (f16, double-buffered in LDS) -> 28 fdot2
// -> pair-sum via shfl_xor(1) -> gate gather via shfl_xor(2/4) -> all 8
// lanes redundantly update c,h -> lane (tid&7)==0 writes h. G rows
// prefetched depth-2 in registers (unroll x2 => static buffer parity);
// count features computed by wave 13 four steps ahead into an 8-slot ring.
// ---------------------------------------------------------------------------
#define OPQ4(v) asm("" : "+v"(v.x), "+v"(v.y), "+v"(v.z), "+v"(v.w))

__global__ void __launch_bounds__(BLK, 1) k_lstm(const int* __restrict__ idx2,
                                                 const float* __restrict__ G,
                                                 const float* __restrict__ base,
                                                 const float* __restrict__ crow0,
                                                 const float* __restrict__ crow1,
                                                 const __half2* __restrict__ Rh2,
                                                 float* __restrict__ h_seq) {
  int b = blockIdx.x;
  int tid = threadIdx.x;

  __shared__ __align__(16) __half h_h[2][112];  // double-buffered packed h
  __shared__ float cnt[NCLS];
  __shared__ float2 ccic_ls[8];                 // ring, written 4 steps ahead
  __shared__ int idx_ls[TT];

  for (int i = tid; i < TT; i += BLK) idx_ls[i] = idx2[(size_t)b * TT + i];
  for (int i = tid; i < NCLS; i += BLK) cnt[i] = 0.0f;
  if (tid < 112) { h_h[0][tid] = __float2half(0.0f); h_h[1][tid] = __float2half(0.0f); }

  int u  = tid >> 3;
  int gt = (tid >> 1) & 3;
  int p  = tid & 1;
  bool dotth = (tid < 800);
  int jj = dotth ? (gt * 100 + u) : 0;

  // weight fragment: 7 float4 = 28 half2 = 56 halves
  const float4* rp = (const float4*)Rh2;   // 14 float4 per column
  int cb = jj * 14 + p * 7;
  float4 w0 = rp[cb + 0], w1 = rp[cb + 1], w2 = rp[cb + 2], w3 = rp[cb + 3];
  float4 w4 = rp[cb + 4], w5 = rp[cb + 5], w6 = rp[cb + 6];
  OPQ4(w0); OPQ4(w1); OPQ4(w2); OPQ4(w3); OPQ4(w4); OPQ4(w5); OPQ4(w6);
  float basej = base[jj], c0j = crow0[jj], c1j = crow1[jj];
  float c_reg = 0.0f;

  __syncthreads();               // idx_ls, cnt, h_h visible

  if (tid == 832) {              // seed count features for t = 0..3
    #pragma unroll
    for (int tt = 0; tt < 4; ++tt) {
      int cls = idx_ls[tt];
      float n = cnt[cls] + 1.0f; cnt[cls] = n;
      float ns = cnt[cls ^ 1];
      float va = (cls & 1) ? ns : n;
      float vb = (cls & 1) ? n : ns;
      ccic_ls[tt] = make_float2(__logf(1.0f + va), __logf(1.0f + vb));
    }
  }
  // G prefetch, depth 2
  float gA = dotth ? G[(size_t)idx_ls[0] * NG + jj] : 0.0f;
  float gB = dotth ? G[(size_t)idx_ls[1] * NG + jj] : 0.0f;

  float* hout = h_seq + (size_t)b * TT * TH;

  #define LSTM_STEP(T, PAR, GVAR)                                              \
  {                                                                            \
    const int t_ = (T);                                                        \
    __syncthreads();  /* the ONE barrier: h(t-1) visible, ccic ring fresh */   \
    if (tid == 832) {                                                          \
      int tn = t_ + 4;                                                         \
      if (tn < TT) {                                                           \
        int cls = idx_ls[tn];                                                  \
        float n = cnt[cls] + 1.0f; cnt[cls] = n;                               \
        float ns = cnt[cls ^ 1];                                               \
        float va = (cls & 1) ? ns : n;                                         \
        float vb = (cls & 1) ? n : ns;                                         \
        ccic_ls[tn & 7] = make_float2(__logf(1.0f + va), __logf(1.0f + vb));   \
      }                                                                        \
    }                                                                          \
    if (dotth) {                                                               \
      const float4* hp = (const float4*)h_h[(PAR) ^ 1];   /* h(t-1) */         \
      float local = dot56(hp, p * 7, w0, w1, w2, w3, w4, w5, w6);              \
      float zsum = local + __shfl_xor(local, 1);          /* pair halves */    \
      float2 cc = ccic_ls[t_ & 7];                                             \
      float z = zsum + (GVAR) + basej + cc.x * c0j + cc.y * c1j;               \
      float act = (gt == 2) ? ftanh(z) : fsig(z);                              \
      float v1 = __shfl_xor(act, 2);                      /* gate gt^1 */      \
      float v2 = __shfl_xor(act, 4);                      /* gate gt^2 */      \
      float v3 = __shfl_xor(v1, 4);                       /* gate gt^3 */      \
      float ai_ = (gt == 0) ? act : ((gt == 1) ? v1 : ((gt == 2) ? v2 : v3));  \
      float af_ = (gt == 1) ? act : ((gt == 0) ? v1 : ((gt == 3) ? v2 : v3));  \
      float ag_ = (gt == 2) ? act : ((gt == 3) ? v1 : ((gt == 0) ? v2 : v3));  \
      float ao_ = (gt == 3) ? act : ((gt == 2) ? v1 : ((gt == 1) ? v2 : v3));  \
      c_reg = af_ * c_reg + ai_ * ag_;                                         \
      float hn = ao_ * ftanh(c_reg);                                           \
      if ((tid & 7) == 0) {                                                    \
        h_h[(PAR)][u] = __float2half_rn(hn);                                   \
        hout[(size_t)t_ * TH + u] = hn;                                        \
      }                                                                        \
      int tn2 = (t_ + 2 < TT) ? t_ + 2 : TT - 1;                               \
      (GVAR) = G[(size_t)idx_ls[tn2] * NG + jj];          /* depth-2 refill */ \
    }                                                                          \
  }

  for (int t2 = 0; t2 < TT; t2 += 2) {
    LSTM_STEP(t2, 0, gA);        // even t: read h_h[1], write h_h[0]
    LSTM_STEP(t2 + 1, 1, gB);    // odd  t: read h_h[0], write h_h[1]
  }
  #undef LSTM_STEP
}

// ---------------------------------------------------------------------------
// Kernel D: out[b,t] = sigmoid( h_seq[b,t] . WoT[qi[b,t]] + bo[qi] )
// ---------------------------------------------------------------------------
__global__ void k_out(const float* __restrict__ h_seq, const float* __restrict__ WoT,
                      const float* __restrict__ bo, const int* __restrict__ qi,
                      float* __restrict__ out) {
  int gid  = blockIdx.x * blockDim.x + threadIdx.x;
  int wave = gid >> 6;
  int lane = threadIdx.x & 63;
  if (wave >= BT) return;
  int s = qi[wave];
  const float4* h4 = (const float4*)(h_seq + (size_t)wave * TH);
  const float4* w4 = (const float4*)(WoT + (size_t)s * TH);
  float acc = 0.0f;
  if (lane < TH / 4) {
    float4 h = h4[lane];
    float4 w = w4[lane];
    acc = h.x * w.x + h.y * w.y + h.z * w.z + h.w * w.w;
  }
  #pragma unroll
  for (int off = 32; off; off >>= 1) acc += __shfl_xor(acc, off);
  if (lane == 0) out[wave] = fsig(acc + bo[s]);
}

// ---------------------------------------------------------------------------
extern "C" void kernel_launch(void* const* d_in, const int* in_sizes, int n_in,
                              void* d_out, int out_size, void* d_ws, size_t ws_size,
                              hipStream_t stream) {
  const float* x    = (const float*)d_in[0];
  // d_in[1] = delta (unused by the reference)
  const float* q    = (const float*)d_in[2];
  const float* Wx   = (const float*)d_in[3];
  const float* bx   = (const float*)d_in[4];
  const float* K    = (const float*)d_in[5];   // lstm_k (103,400)
  const float* R    = (const float*)d_in[6];   // lstm_rk (100,400)
  const float* lb   = (const float*)d_in[7];   // lstm_b (400)
  const float* Wo   = (const float*)d_in[8];   // (100,200)
  const float* bo   = (const float*)d_in[9];   // (200)
  float* out = (float*)d_out;

  // workspace layout (floats)
  float* ws = (float*)d_ws;
  float*   G      = ws;                      // 160000
  float*   base   = ws + 160000;             // 400
  float*   crow0  = ws + 160400;             // 400
  float*   crow1  = ws + 160800;             // 400
  float*   WoT    = ws + 161200;             // 20000
  __half2* Rh2    = (__half2*)(ws + 181200); // 22400 half2 = 22400 floats
  int*     idx2   = (int*)(ws + 203600);     // 64000
  int*     qi     = (int*)(ws + 267600);     // 64000
  float*   h_seq  = ws + 331600;             // 6,400,000
  // total: 6,731,600 floats = 26.9 MB

  // A: compress one-hots
  k_compress<<<BT / 4, 256, 0, stream>>>(x, q, idx2, qi);

  // B: precompute tables (G, base, count rows, WoT, packed-f16 R)
  int tail_blocks = (TS * TH + NG * 56 + 511) / 512;     // 83
  k_precompute<<<NCLS + 1 + tail_blocks, 512, 0, stream>>>(Wx, bx, K, lb, Wo, R,
                                                           G, base, crow0, crow1, WoT, Rh2);

  // C: sequential LSTM, one block per batch element
  k_lstm<<<TB, BLK, 0, stream>>>(idx2, G, base, crow0, crow1, Rh2, h_seq);

  // D: gather + dot + sigmoid
  k_out<<<BT / 4, 256, 0, stream>>>(h_seq, WoT, bo, qi, out);
}

// Round 7
// 543.465 us; speedup vs baseline: 1.0018x; 1.0018x over previous
//
#include <hip/hip_runtime.h>
#include <hip/hip_bf16.h>
#include <hip/hip_fp16.h>

// Problem constants
#define TB 128
#define TT 500
#define TS 200
#define TE 100
#define TH 100
#define NCLS 400              // 2*S  (one-hot width of x)
#define NG   400              // 4*H  (gate width)
#define BT   (TB*TT)          // 64000 (b,t) pairs
#define BLK  896              // 14 waves: 0-12 dot (800 active), wave 13 = count scan
#define HROW 112              // padded h row (halves); 224 B = 14 float4

typedef _Float16 h2_t __attribute__((ext_vector_type(2)));
union U16 { float4 f4; h2_t h[4]; };

__device__ __forceinline__ float fsig(float x) { return 1.0f / (1.0f + __expf(-x)); }
__device__ __forceinline__ float ftanh(float x) { float e = __expf(2.0f * x); return 1.0f - 2.0f / (e + 1.0f); }

// LDS-only barrier: drain lgkm (ds ops) but leave global loads in flight.
// (__syncthreads would emit s_waitcnt vmcnt(0) before s_barrier — that drain
// of in-loop global ops was the ~1500 cyc/step stall in rounds 1-6.)
__device__ __forceinline__ void barrier_lds() {
  asm volatile("s_waitcnt lgkmcnt(0)\n\ts_barrier" ::: "memory");
}

__device__ __forceinline__ float FDOT2(h2_t a, h2_t b, float c) {
#if __has_builtin(__builtin_amdgcn_fdot2)
  return __builtin_amdgcn_fdot2(a, b, c, false);
#else
  return c + (float)a.x * (float)b.x + (float)a.y * (float)b.y;
#endif
}

// 56-half dot: 7 float4 of packed f16 weights against 7 float4 of packed h
__device__ __forceinline__ float dot56(const float4* hp, int hb,
                                       const float4& w0, const float4& w1,
                                       const float4& w2, const float4& w3,
                                       const float4& w4, const float4& w5,
                                       const float4& w6) {
  float a0 = 0.0f, a1 = 0.0f;
  #define DOTC(c, wr) { U16 uh, uw; uh.f4 = hp[hb + c]; uw.f4 = wr; \
    a0 = FDOT2(uh.h[0], uw.h[0], a0); a1 = FDOT2(uh.h[1], uw.h[1], a1); \
    a0 = FDOT2(uh.h[2], uw.h[2], a0); a1 = FDOT2(uh.h[3], uw.h[3], a1); }
  DOTC(0, w0) DOTC(1, w1) DOTC(2, w2) DOTC(3, w3)
  DOTC(4, w4) DOTC(5, w5) DOTC(6, w6)
  #undef DOTC
  return a0 + a1;
}

// ---------------------------------------------------------------------------
// Kernel A: compress one-hot x (B,T,400) -> idx2 and q (B,T,200) -> qi.
// One wave per (b,t).
// ---------------------------------------------------------------------------
__global__ void k_compress(const float* __restrict__ x, const float* __restrict__ q,
                           int* __restrict__ idx2, int* __restrict__ qi) {
  int gid  = blockIdx.x * blockDim.x + threadIdx.x;
  int wave = gid >> 6;
  int lane = threadIdx.x & 63;
  if (wave >= BT) return;

  const float4* xr = (const float4*)(x + (size_t)wave * NCLS);
  int li = -1;
  {
    float4 v = xr[lane];
    if (v.x > 0.5f) li = lane * 4 + 0;
    if (v.y > 0.5f) li = lane * 4 + 1;
    if (v.z > 0.5f) li = lane * 4 + 2;
    if (v.w > 0.5f) li = lane * 4 + 3;
    int ci = 64 + lane;
    if (ci < 100) {
      float4 w = xr[ci];
      if (w.x > 0.5f) li = ci * 4 + 0;
      if (w.y > 0.5f) li = ci * 4 + 1;
      if (w.z > 0.5f) li = ci * 4 + 2;
      if (w.w > 0.5f) li = ci * 4 + 3;
    }
  }
  #pragma unroll
  for (int off = 32; off; off >>= 1) li = max(li, __shfl_xor(li, off));

  const float4* qr = (const float4*)(q + (size_t)wave * TS);
  int qj = -1;
  if (lane < 50) {
    float4 v = qr[lane];
    if (v.x > 0.5f) qj = lane * 4 + 0;
    if (v.y > 0.5f) qj = lane * 4 + 1;
    if (v.z > 0.5f) qj = lane * 4 + 2;
    if (v.w > 0.5f) qj = lane * 4 + 3;
  }
  #pragma unroll
  for (int off = 32; off; off >>= 1) qj = max(qj, __shfl_xor(qj, off));

  if (lane == 0) { idx2[wave] = li; qi[wave] = qj; }
}

// ---------------------------------------------------------------------------
// Kernel B: precompute Gp (owner-permuted gather table), base, count rows,
// Wo^T, packed-f16 R columns.
// Owner ow = 4u+gt owns gate-column jj = gt*100+u; Gp[cls][ow] = G[cls][jj]
// so the per-step wave gather is CONTIGUOUS (2 lanes broadcast per dword).
// ---------------------------------------------------------------------------
__global__ void k_precompute(const float* __restrict__ Wx, const float* __restrict__ bx,
                             const float* __restrict__ K, const float* __restrict__ lb,
                             const float* __restrict__ Wo, const float* __restrict__ R,
                             float* __restrict__ Gp, float* __restrict__ base,
                             float* __restrict__ crow0, float* __restrict__ crow1,
                             float* __restrict__ WoT, __half2* __restrict__ Rh2) {
  int bid = blockIdx.x, tid = threadIdx.x;
  if (bid < NCLS) {
    if (tid < NG) {
      float acc = 0.0f;
      for (int e = 0; e < TE; ++e) acc = fmaf(Wx[bid * TE + e], K[e * NG + tid], acc);
      int u = tid % 100, gt = tid / 100;
      Gp[bid * NG + 4 * u + gt] = acc;
    }
  } else if (bid == NCLS) {
    if (tid < NG) {
      float acc = lb[tid];
      for (int e = 0; e < TE; ++e) acc = fmaf(bx[e], K[e * NG + tid], acc);
      base[tid]  = acc;
      crow0[tid] = K[100 * NG + tid] + K[102 * NG + tid];
      crow1[tid] = K[101 * NG + tid] + K[102 * NG + tid];
    }
  } else {
    int id = (bid - NCLS - 1) * 512 + tid;
    if (id < TS * TH) {
      int s = id / TH, k = id % TH;
      WoT[id] = Wo[k * TS + s];
    } else {
      int id2 = id - TS * TH;
      if (id2 < NG * 56) {
        int j = id2 / 56, m = id2 % 56;
        int k0 = 2 * m, k1 = 2 * m + 1;
        float a = (k0 < TH) ? R[k0 * NG + j] : 0.0f;
        float b = (k1 < TH) ? R[k1 * NG + j] : 0.0f;
        Rh2[id2] = __halves2half2(__float2half_rn(a), __float2half_rn(b));
      }
    }
  }
}

// ---------------------------------------------------------------------------
// Kernel C: LSTM recurrence with ZERO global traffic on the barrier path.
// One block per batch b. Thread tid = 8u + 2*gt + p (tid<800): unit u,
// gate gt, half-column p; 28 pinned VGPRs of packed-f16 weights each.
// The ENTIRE h history lives in LDS (hb[501][112] f16, 112 KB): step t
// reads row t-1 (broadcast float4), writes row t; row 500 is the zero
// initial state. No hout store in the loop; barriers drain lgkm ONLY.
// G rows prefetched depth-2 into registers, refilled at the TOP of the
// step. Gate gather: 3 INDEPENDENT shfl_xor (2,4,6) — one latency.
// Count features: wave 13, 4 steps ahead, 8-slot LDS ring.
// Epilogue: coalesced f16->f32 dump of hb into h_seq.
// ---------------------------------------------------------------------------
#define OPQ4(v) asm("" : "+v"(v.x), "+v"(v.y), "+v"(v.z), "+v"(v.w))

__global__ void __launch_bounds__(BLK, 1) k_lstm(const int* __restrict__ idx2,
                                                 const float* __restrict__ Gp,
                                                 const float* __restrict__ base,
                                                 const float* __restrict__ crow0,
                                                 const float* __restrict__ crow1,
                                                 const __half2* __restrict__ Rh2,
                                                 float* __restrict__ h_seq) {
  extern __shared__ char smem[];
  __half* hb     = (__half*)smem;                               // 501*112 halves
  float4* hb4    = (float4*)smem;                               // 7014 float4
  float*  cnt    = (float*)(smem + 501 * 224);                  // 400 floats
  float2* ccic   = (float2*)(smem + 501 * 224 + 1600);          // 8 float2
  int*    idx_ls = (int*)(smem + 501 * 224 + 1664);             // 500 ints

  int b = blockIdx.x;
  int tid = threadIdx.x;

  for (int i = tid; i < 7014; i += BLK) hb4[i] = make_float4(0.f, 0.f, 0.f, 0.f);
  for (int i = tid; i < NCLS; i += BLK) cnt[i] = 0.0f;
  for (int i = tid; i < TT; i += BLK) idx_ls[i] = idx2[(size_t)b * TT + i];

  int u  = tid >> 3;
  int gt = (tid >> 1) & 3;
  int p  = tid & 1;
  bool dotth = (tid < 800);
  int jj = dotth ? (gt * 100 + u) : 0;
  int ow = dotth ? (tid >> 1) : 0;

  // weight fragment: 7 float4 = 56 packed halves
  const float4* rp = (const float4*)Rh2;   // 14 float4 per column
  int cb = jj * 14 + p * 7;
  float4 w0 = rp[cb + 0], w1 = rp[cb + 1], w2 = rp[cb + 2], w3 = rp[cb + 3];
  float4 w4 = rp[cb + 4], w5 = rp[cb + 5], w6 = rp[cb + 6];
  OPQ4(w0); OPQ4(w1); OPQ4(w2); OPQ4(w3); OPQ4(w4); OPQ4(w5); OPQ4(w6);
  float basej = base[jj], c0j = crow0[jj], c1j = crow1[jj];
  float c_reg = 0.0f;

  __syncthreads();               // init visible (full barrier OK outside loop)

  if (tid == 832) {              // seed count features for t = 0..3
    #pragma unroll
    for (int tt = 0; tt < 4; ++tt) {
      int cls = idx_ls[tt];
      float n = cnt[cls] + 1.0f; cnt[cls] = n;
      float ns = cnt[cls ^ 1];
      float va = (cls & 1) ? ns : n;
      float vb = (cls & 1) ? n : ns;
      ccic[tt] = make_float2(__logf(1.0f + va), __logf(1.0f + vb));
    }
  }
  // G prefetch, depth 2
  float gA = dotth ? Gp[(size_t)idx_ls[0] * NG + ow] : 0.0f;
  float gB = dotth ? Gp[(size_t)idx_ls[1] * NG + ow] : 0.0f;

  #define LSTM_STEP(T, GVAR)                                                   \
  {                                                                            \
    const int t_ = (T);                                                        \
    barrier_lds();  /* h(t-1) + ccic visible; G loads stay in flight */        \
    if (tid == 832) {                                                          \
      int tn = t_ + 4;                                                         \
      if (tn < TT) {                                                           \
        int cls = idx_ls[tn];                                                  \
        float n = cnt[cls] + 1.0f; cnt[cls] = n;                               \
        float ns = cnt[cls ^ 1];                                               \
        float va = (cls & 1) ? ns : n;                                         \
        float vb = (cls & 1) ? n : ns;                                         \
        ccic[tn & 7] = make_float2(__logf(1.0f + va), __logf(1.0f + vb));      \
      }                                                                        \
    }                                                                          \
    if (dotth) {                                                               \
      float gv = (GVAR);                                                       \
      int tn2 = (t_ + 2 < TT) ? t_ + 2 : TT - 1;                               \
      (GVAR) = Gp[(size_t)idx_ls[tn2] * NG + ow];   /* refill EARLY */         \
      const float4* hp = hb4 + ((t_ == 0) ? TT : t_ - 1) * 14;                 \
      float local = dot56(hp, p * 7, w0, w1, w2, w3, w4, w5, w6);              \
      float zsum = local + __shfl_xor(local, 1);          /* pair halves */    \
      float2 cc = ccic[t_ & 7];                                                \
      float z = zsum + gv + basej + cc.x * c0j + cc.y * c1j;                   \
      float act = (gt == 2) ? ftanh(z) : fsig(z);                              \
      float v1 = __shfl_xor(act, 2);   /* independent */                       \
      float v2 = __shfl_xor(act, 4);   /* independent */                       \
      float v3 = __shfl_xor(act, 6);   /* independent (xor2^xor4) */           \
      float ai_ = (gt == 0) ? act : ((gt == 1) ? v1 : ((gt == 2) ? v2 : v3));  \
      float af_ = (gt == 1) ? act : ((gt == 0) ? v1 : ((gt == 3) ? v2 : v3));  \
      float ag_ = (gt == 2) ? act : ((gt == 3) ? v1 : ((gt == 0) ? v2 : v3));  \
      float ao_ = (gt == 3) ? act : ((gt == 2) ? v1 : ((gt == 1) ? v2 : v3));  \
      c_reg = af_ * c_reg + ai_ * ag_;                                         \
      float hn = ao_ * ftanh(c_reg);                                           \
      if ((tid & 7) == 0) hb[t_ * HROW + u] = __float2half_rn(hn);             \
    }                                                                          \
  }

  for (int t2 = 0; t2 < TT; t2 += 2) {
    LSTM_STEP(t2, gA);
    LSTM_STEP(t2 + 1, gB);
  }
  #undef LSTM_STEP

  __syncthreads();               // all hb rows final
  // epilogue: coalesced f16 -> f32 dump
  float* hout = h_seq + (size_t)b * TT * TH;
  for (int i = tid; i < TT * TH; i += BLK) {
    int t = i / TH, uu = i % TH;
    hout[i] = __half2float(hb[t * HROW + uu]);
  }
}

// ---------------------------------------------------------------------------
// Kernel D: out[b,t] = sigmoid( h_seq[b,t] . WoT[qi[b,t]] + bo[qi] )
// ---------------------------------------------------------------------------
__global__ void k_out(const float* __restrict__ h_seq, const float* __restrict__ WoT,
                      const float* __restrict__ bo, const int* __restrict__ qi,
                      float* __restrict__ out) {
  int gid  = blockIdx.x * blockDim.x + threadIdx.x;
  int wave = gid >> 6;
  int lane = threadIdx.x & 63;
  if (wave >= BT) return;
  int s = qi[wave];
  const float4* h4 = (const float4*)(h_seq + (size_t)wave * TH);
  const float4* w4 = (const float4*)(WoT + (size_t)s * TH);
  float acc = 0.0f;
  if (lane < TH / 4) {
    float4 h = h4[lane];
    float4 w = w4[lane];
    acc = h.x * w.x + h.y * w.y + h.z * w.z + h.w * w.w;
  }
  #pragma unroll
  for (int off = 32; off; off >>= 1) acc += __shfl_xor(acc, off);
  if (lane == 0) out[wave] = fsig(acc + bo[s]);
}

// ---------------------------------------------------------------------------
extern "C" void kernel_launch(void* const* d_in, const int* in_sizes, int n_in,
                              void* d_out, int out_size, void* d_ws, size_t ws_size,
                              hipStream_t stream) {
  const float* x    = (const float*)d_in[0];
  // d_in[1] = delta (unused by the reference)
  const float* q    = (const float*)d_in[2];
  const float* Wx   = (const float*)d_in[3];
  const float* bx   = (const float*)d_in[4];
  const float* K    = (const float*)d_in[5];   // lstm_k (103,400)
  const float* R    = (const float*)d_in[6];   // lstm_rk (100,400)
  const float* lb   = (const float*)d_in[7];   // lstm_b (400)
  const float* Wo   = (const float*)d_in[8];   // (100,200)
  const float* bo   = (const float*)d_in[9];   // (200)
  float* out = (float*)d_out;

  // workspace layout (floats)
  float* ws = (float*)d_ws;
  float*   Gp     = ws;                      // 160000
  float*   base   = ws + 160000;             // 400
  float*   crow0  = ws + 160400;             // 400
  float*   crow1  = ws + 160800;             // 400
  float*   WoT    = ws + 161200;             // 20000
  __half2* Rh2    = (__half2*)(ws + 181200); // 22400 half2 = 22400 floats
  int*     idx2   = (int*)(ws + 203600);     // 64000
  int*     qi     = (int*)(ws + 267600);     // 64000
  float*   h_seq  = ws + 331600;             // 6,400,000
  // total: 6,731,600 floats = 26.9 MB

  // A: compress one-hots
  k_compress<<<BT / 4, 256, 0, stream>>>(x, q, idx2, qi);

  // B: precompute tables (Gp, base, count rows, WoT, packed-f16 R)
  int tail_blocks = (TS * TH + NG * 56 + 511) / 512;     // 83
  k_precompute<<<NCLS + 1 + tail_blocks, 512, 0, stream>>>(Wx, bx, K, lb, Wo, R,
                                                           Gp, base, crow0, crow1, WoT, Rh2);

  // C: sequential LSTM, one block per batch element; h history in LDS
  size_t shmem = 501 * 224 + 1600 + 64 + 2000;           // 115,888 B
  k_lstm<<<TB, BLK, shmem, stream>>>(idx2, Gp, base, crow0, crow1, Rh2, h_seq);

  // D: gather + dot + sigmoid
  k_out<<<BT / 4, 256, 0, stream>>>(h_seq, WoT, bo, qi, out);
}

// Round 8
// 479.261 us; speedup vs baseline: 1.1360x; 1.1340x over previous
//
#include <hip/hip_runtime.h>
#include <hip/hip_bf16.h>
#include <hip/hip_fp16.h>

// Problem constants
#define TB 128
#define TT 500
#define TS 200
#define TE 100
#define TH 100
#define NCLS 400              // 2*S  (one-hot width of x)
#define NG   400              // 4*H  (gate width)
#define BT   (TB*TT)          // 64000 (b,t) pairs
#define BLK  512              // 8 waves: 0-6 dot (400 active), wave 7 = count scan
#define NDOT 400              // dot threads: t = 4u + 2e + p

typedef _Float16 h2_t __attribute__((ext_vector_type(2)));
union U16 { float4 f4; h2_t h[4]; };

__device__ __forceinline__ float fsig(float x) { return 1.0f / (1.0f + __expf(-x)); }
__device__ __forceinline__ float ftanh(float x) { float e = __expf(2.0f * x); return 1.0f - 2.0f / (e + 1.0f); }

// LDS-only barrier: drain lgkm (ds ops) but leave global loads/stores in flight.
__device__ __forceinline__ void barrier_lds() {
  asm volatile("s_waitcnt lgkmcnt(0)\n\ts_barrier" ::: "memory");
}

__device__ __forceinline__ float FDOT2(h2_t a, h2_t b, float c) {
#if __has_builtin(__builtin_amdgcn_fdot2)
  return __builtin_amdgcn_fdot2(a, b, c, false);
#else
  return c + (float)a.x * (float)b.x + (float)a.y * (float)b.y;
#endif
}

// ---------------------------------------------------------------------------
// Kernel A: compress one-hot x (B,T,400) -> idx2 and q (B,T,200) -> qi.
// One wave per (b,t).
// ---------------------------------------------------------------------------
__global__ void k_compress(const float* __restrict__ x, const float* __restrict__ q,
                           int* __restrict__ idx2, int* __restrict__ qi) {
  int gid  = blockIdx.x * blockDim.x + threadIdx.x;
  int wave = gid >> 6;
  int lane = threadIdx.x & 63;
  if (wave >= BT) return;

  const float4* xr = (const float4*)(x + (size_t)wave * NCLS);
  int li = -1;
  {
    float4 v = xr[lane];
    if (v.x > 0.5f) li = lane * 4 + 0;
    if (v.y > 0.5f) li = lane * 4 + 1;
    if (v.z > 0.5f) li = lane * 4 + 2;
    if (v.w > 0.5f) li = lane * 4 + 3;
    int ci = 64 + lane;
    if (ci < 100) {
      float4 w = xr[ci];
      if (w.x > 0.5f) li = ci * 4 + 0;
      if (w.y > 0.5f) li = ci * 4 + 1;
      if (w.z > 0.5f) li = ci * 4 + 2;
      if (w.w > 0.5f) li = ci * 4 + 3;
    }
  }
  #pragma unroll
  for (int off = 32; off; off >>= 1) li = max(li, __shfl_xor(li, off));

  const float4* qr = (const float4*)(q + (size_t)wave * TS);
  int qj = -1;
  if (lane < 50) {
    float4 v = qr[lane];
    if (v.x > 0.5f) qj = lane * 4 + 0;
    if (v.y > 0.5f) qj = lane * 4 + 1;
    if (v.z > 0.5f) qj = lane * 4 + 2;
    if (v.w > 0.5f) qj = lane * 4 + 3;
  }
  #pragma unroll
  for (int off = 32; off; off >>= 1) qj = max(qj, __shfl_xor(qj, off));

  if (lane == 0) { idx2[wave] = li; qi[wave] = qj; }
}

// ---------------------------------------------------------------------------
// Kernel B: precompute Gp (quad-permuted gather table), base, count rows,
// Wo^T, thread-layout packed-f16 R fragments.
// Thread t = 4u+2e+p owns halves [p*56, p*56+56) of colA = e?100+u:u and
// colB = e?300+u:200+u. Rwh2[t*56 + which*28 + m].
// Gp float2 per (cls, pair pr=2u+e): (.x,.y) = (G[cls][colA], G[cls][colB]).
// ---------------------------------------------------------------------------
__global__ void k_precompute(const float* __restrict__ Wx, const float* __restrict__ bx,
                             const float* __restrict__ K, const float* __restrict__ lb,
                             const float* __restrict__ Wo, const float* __restrict__ R,
                             float* __restrict__ Gp, float* __restrict__ base,
                             float* __restrict__ crow0, float* __restrict__ crow1,
                             float* __restrict__ WoT, __half2* __restrict__ Rwh2) {
  int bid = blockIdx.x, tid = threadIdx.x;
  if (bid < NCLS) {
    if (tid < NG) {
      float acc = 0.0f;
      for (int e = 0; e < TE; ++e) acc = fmaf(Wx[bid * TE + e], K[e * NG + tid], acc);
      int gt = tid / 100, u = tid % 100;
      int ee = gt & 1, slot = gt >> 1;        // i:(e0,s0) f:(e1,s0) g:(e0,s1) o:(e1,s1)
      int pr = 2 * u + ee;
      Gp[bid * NG + pr * 2 + slot] = acc;
    }
  } else if (bid == NCLS) {
    if (tid < NG) {
      float acc = lb[tid];
      for (int e = 0; e < TE; ++e) acc = fmaf(bx[e], K[e * NG + tid], acc);
      base[tid]  = acc;
      crow0[tid] = K[100 * NG + tid] + K[102 * NG + tid];
      crow1[tid] = K[101 * NG + tid] + K[102 * NG + tid];
    }
  } else {
    int id = (bid - NCLS - 1) * 512 + tid;
    if (id < TS * TH) {
      int s = id / TH, k = id % TH;
      WoT[id] = Wo[k * TS + s];
    } else {
      int id2 = id - TS * TH;
      if (id2 < NDOT * 56) {
        int t = id2 / 56, r = id2 % 56;
        int u = t >> 2, e = (t >> 1) & 1, p = t & 1;
        int which = r / 28, ml = r % 28;
        int col = which ? (e ? 300 + u : 200 + u) : (e ? 100 + u : u);
        int k0 = p * 56 + 2 * ml, k1 = k0 + 1;
        float a = (k0 < TH) ? R[k0 * NG + col] : 0.0f;
        float b = (k1 < TH) ? R[k1 * NG + col] : 0.0f;
        Rwh2[id2] = __halves2half2(__float2half_rn(a), __float2half_rn(b));
      }
    }
  }
}

// ---------------------------------------------------------------------------
// Kernel C: LSTM recurrence, quad-per-unit. One block per batch b, 512 thr.
// t = 4u + 2e + p (t<400): unit u, gate-pair e (0:i,g  1:f,o), K-half p.
// 14 pinned float4 (56 VGPRs) of packed-f16 weights per thread. h in a
// 2-row f16 LDS double buffer (448 B — no history; h_seq stores fly out
// un-drained since barriers wait lgkm only). Per step: ONE barrier,
// 7 b128 h-reads/thread (49/step vs 91 in R5-R7 — the DS-return-BW wall),
// 56 fdot2, halves via shfl_xor(1), gates via shfl_xor(2), redundant
// quad c/h update. G float2 prefetch depth-2. Scan thread = 448 (wave 7).
// ---------------------------------------------------------------------------
#define OPQ4(v) asm("" : "+v"(v.x), "+v"(v.y), "+v"(v.z), "+v"(v.w))

__global__ void __attribute__((amdgpu_flat_work_group_size(BLK, BLK),
                               amdgpu_waves_per_eu(1, 2)))
k_lstm(const int* __restrict__ idx2,
       const float* __restrict__ Gp,
       const float* __restrict__ base,
       const float* __restrict__ crow0,
       const float* __restrict__ crow1,
       const __half2* __restrict__ Rwh2,
       float* __restrict__ h_seq) {
  __shared__ __align__(16) __half hbuf[2][112];   // double-buffered packed h
  __shared__ float cnt[NCLS];
  __shared__ float2 ccic[8];                      // ring, written 4 steps ahead
  __shared__ int idx_ls[TT];

  int b = blockIdx.x;
  int tid = threadIdx.x;

  for (int i = tid; i < TT; i += BLK) idx_ls[i] = idx2[(size_t)b * TT + i];
  for (int i = tid; i < NCLS; i += BLK) cnt[i] = 0.0f;
  if (tid < 112) { hbuf[0][tid] = __float2half(0.0f); hbuf[1][tid] = __float2half(0.0f); }

  int u = tid >> 2;
  int e = (tid >> 1) & 1;
  int p = tid & 1;
  bool dotth = (tid < NDOT);
  int colA = dotth ? (e ? 100 + u : u) : 0;
  int colB = dotth ? (e ? 300 + u : 200 + u) : 0;
  int pr   = dotth ? (tid >> 1) : 0;             // 2u + e

  // weight fragment: 14 float4 = 56 h2 (two half-columns)
  const float4* rp = (const float4*)Rwh2;        // 14 float4 per thread
  int cb = (dotth ? tid : 0) * 14;
  float4 wA0 = rp[cb + 0], wA1 = rp[cb + 1], wA2 = rp[cb + 2], wA3 = rp[cb + 3];
  float4 wA4 = rp[cb + 4], wA5 = rp[cb + 5], wA6 = rp[cb + 6];
  float4 wB0 = rp[cb + 7], wB1 = rp[cb + 8], wB2 = rp[cb + 9], wB3 = rp[cb + 10];
  float4 wB4 = rp[cb + 11], wB5 = rp[cb + 12], wB6 = rp[cb + 13];
  OPQ4(wA0); OPQ4(wA1); OPQ4(wA2); OPQ4(wA3); OPQ4(wA4); OPQ4(wA5); OPQ4(wA6);
  OPQ4(wB0); OPQ4(wB1); OPQ4(wB2); OPQ4(wB3); OPQ4(wB4); OPQ4(wB5); OPQ4(wB6);
  float baseA = base[colA], c0A = crow0[colA], c1A = crow1[colA];
  float baseB = base[colB], c0B = crow0[colB], c1B = crow1[colB];
  float c_reg = 0.0f;

  __syncthreads();               // init visible

  if (tid == 448) {              // seed count features for t = 0..3
    #pragma unroll
    for (int tt = 0; tt < 4; ++tt) {
      int cls = idx_ls[tt];
      float n = cnt[cls] + 1.0f; cnt[cls] = n;
      float ns = cnt[cls ^ 1];
      float va = (cls & 1) ? ns : n;
      float vb = (cls & 1) ? n : ns;
      ccic[tt] = make_float2(__logf(1.0f + va), __logf(1.0f + vb));
    }
  }
  // G prefetch (float2 per pair), depth 2
  const float2* Gp2 = (const float2*)Gp;
  float2 gA = dotth ? Gp2[(size_t)idx_ls[0] * 200 + pr] : make_float2(0.f, 0.f);
  float2 gB = dotth ? Gp2[(size_t)idx_ls[1] * 200 + pr] : make_float2(0.f, 0.f);

  float* hout = h_seq + (size_t)b * TT * TH;

  #define LSTM_STEP(T, PAR, GVAR)                                              \
  {                                                                            \
    const int t_ = (T);                                                        \
    barrier_lds();  /* h(t-1) + ccic visible; global ops stay in flight */     \
    if (tid == 448) {                                                          \
      int tn = t_ + 4;                                                         \
      if (tn < TT) {                                                           \
        int cls = idx_ls[tn];                                                  \
        float n = cnt[cls] + 1.0f; cnt[cls] = n;                               \
        float ns = cnt[cls ^ 1];                                               \
        float va = (cls & 1) ? ns : n;                                         \
        float vb = (cls & 1) ? n : ns;                                         \
        ccic[tn & 7] = make_float2(__logf(1.0f + va), __logf(1.0f + vb));      \
      }                                                                        \
    }                                                                          \
    if (dotth) {                                                               \
      float2 gv = (GVAR);                                                      \
      int tn2 = (t_ + 2 < TT) ? t_ + 2 : TT - 1;                               \
      (GVAR) = Gp2[(size_t)idx_ls[tn2] * 200 + pr];     /* refill EARLY */     \
      const float4* hp = ((const float4*)&hbuf[(PAR) ^ 1][0]) + p * 7;         \
      float aA0 = 0.f, aA1 = 0.f, aB0 = 0.f, aB1 = 0.f;                        \
      _Pragma("unroll")                                                        \
      for (int c = 0; c < 7; ++c) {                                            \
        U16 uh; uh.f4 = hp[c];                                                 \
        U16 ua; ua.f4 = (c==0?wA0:c==1?wA1:c==2?wA2:c==3?wA3:c==4?wA4:c==5?wA5:wA6); \
        U16 ub; ub.f4 = (c==0?wB0:c==1?wB1:c==2?wB2:c==3?wB3:c==4?wB4:c==5?wB5:wB6); \
        aA0 = FDOT2(uh.h[0], ua.h[0], aA0); aA1 = FDOT2(uh.h[1], ua.h[1], aA1);\
        aA0 = FDOT2(uh.h[2], ua.h[2], aA0); aA1 = FDOT2(uh.h[3], ua.h[3], aA1);\
        aB0 = FDOT2(uh.h[0], ub.h[0], aB0); aB1 = FDOT2(uh.h[1], ub.h[1], aB1);\
        aB0 = FDOT2(uh.h[2], ub.h[2], aB0); aB1 = FDOT2(uh.h[3], ub.h[3], aB1);\
      }                                                                        \
      float hA = aA0 + aA1, hB = aB0 + aB1;                                    \
      float zA = hA + __shfl_xor(hA, 1);          /* combine K-halves */       \
      float zB = hB + __shfl_xor(hB, 1);                                       \
      float2 cc = ccic[t_ & 7];                                                \
      zA += gv.x + baseA + cc.x * c0A + cc.y * c1A;                            \
      zB += gv.y + baseB + cc.x * c0B + cc.y * c1B;                            \
      float actA = fsig(zA);                      /* i (e0) or f (e1) */       \
      float actB = e ? fsig(zB) : ftanh(zB);      /* o (e1) or g (e0) */       \
      float xA = __shfl_xor(actA, 2);             /* swap gate pairs */        \
      float xB = __shfl_xor(actB, 2);                                          \
      float ai = e ? xA : actA;                                                \
      float af = e ? actA : xA;                                                \
      float ag = e ? xB : actB;                                                \
      float ao = e ? actB : xB;                                                \
      c_reg = af * c_reg + ai * ag;                                            \
      float hn = ao * ftanh(c_reg);                                            \
      if ((tid & 3) == 0) {                                                    \
        hbuf[(PAR)][u] = __float2half_rn(hn);                                  \
        hout[(size_t)t_ * TH + u] = hn;           /* un-drained store */       \
      }                                                                        \
    }                                                                          \
  }

  for (int t2 = 0; t2 < TT; t2 += 2) {
    LSTM_STEP(t2, 0, gA);        // even t: read hbuf[1], write hbuf[0]
    LSTM_STEP(t2 + 1, 1, gB);    // odd  t: read hbuf[0], write hbuf[1]
  }
  #undef LSTM_STEP
}

// ---------------------------------------------------------------------------
// Kernel D: out[b,t] = sigmoid( h_seq[b,t] . WoT[qi[b,t]] + bo[qi] )
// ---------------------------------------------------------------------------
__global__ void k_out(const float* __restrict__ h_seq, const float* __restrict__ WoT,
                      const float* __restrict__ bo, const int* __restrict__ qi,
                      float* __restrict__ out) {
  int gid  = blockIdx.x * blockDim.x + threadIdx.x;
  int wave = gid >> 6;
  int lane = threadIdx.x & 63;
  if (wave >= BT) return;
  int s = qi[wave];
  const float4* h4 = (const float4*)(h_seq + (size_t)wave * TH);
  const float4* w4 = (const float4*)(WoT + (size_t)s * TH);
  float acc = 0.0f;
  if (lane < TH / 4) {
    float4 h = h4[lane];
    float4 w = w4[lane];
    acc = h.x * w.x + h.y * w.y + h.z * w.z + h.w * w.w;
  }
  #pragma unroll
  for (int off = 32; off; off >>= 1) acc += __shfl_xor(acc, off);
  if (lane == 0) out[wave] = fsig(acc + bo[s]);
}

// ---------------------------------------------------------------------------
extern "C" void kernel_launch(void* const* d_in, const int* in_sizes, int n_in,
                              void* d_out, int out_size, void* d_ws, size_t ws_size,
                              hipStream_t stream) {
  const float* x    = (const float*)d_in[0];
  // d_in[1] = delta (unused by the reference)
  const float* q    = (const float*)d_in[2];
  const float* Wx   = (const float*)d_in[3];
  const float* bx   = (const float*)d_in[4];
  const float* K    = (const float*)d_in[5];   // lstm_k (103,400)
  const float* R    = (const float*)d_in[6];   // lstm_rk (100,400)
  const float* lb   = (const float*)d_in[7];   // lstm_b (400)
  const float* Wo   = (const float*)d_in[8];   // (100,200)
  const float* bo   = (const float*)d_in[9];   // (200)
  float* out = (float*)d_out;

  // workspace layout (floats)
  float* ws = (float*)d_ws;
  float*   Gp     = ws;                      // 160000
  float*   base   = ws + 160000;             // 400
  float*   crow0  = ws + 160400;             // 400
  float*   crow1  = ws + 160800;             // 400
  float*   WoT    = ws + 161200;             // 20000
  __half2* Rwh2   = (__half2*)(ws + 181200); // 22400 half2 = 22400 floats
  int*     idx2   = (int*)(ws + 203600);     // 64000
  int*     qi     = (int*)(ws + 267600);     // 64000
  float*   h_seq  = ws + 331600;             // 6,400,000
  // total: 6,731,600 floats = 26.9 MB

  // A: compress one-hots
  k_compress<<<BT / 4, 256, 0, stream>>>(x, q, idx2, qi);

  // B: precompute tables (Gp, base, count rows, WoT, thread-packed f16 R)
  int tail_blocks = (TS * TH + NDOT * 56 + 511) / 512;   // 83
  k_precompute<<<NCLS + 1 + tail_blocks, 512, 0, stream>>>(Wx, bx, K, lb, Wo, R,
                                                           Gp, base, crow0, crow1, WoT, Rwh2);

  // C: sequential LSTM, one block per batch element
  k_lstm<<<TB, BLK, 0, stream>>>(idx2, Gp, base, crow0, crow1, Rwh2, h_seq);

  // D: gather + dot + sigmoid
  k_out<<<BT / 4, 256, 0, stream>>>(h_seq, WoT, bo, qi, out);
}

// Round 10
// 449.568 us; speedup vs baseline: 1.2110x; 1.0660x over previous
//
#include <hip/hip_runtime.h>
#include <hip/hip_bf16.h>
#include <hip/hip_fp16.h>

// Problem constants
#define TB 128
#define TT 500
#define TS 200
#define TE 100
#define TH 100
#define NCLS 400              // 2*S  (one-hot width of x)
#define NG   400              // 4*H  (gate width)
#define BT   (TB*TT)          // 64000 (b,t) pairs
#define BLK  448              // 7 waves x 4 tile-slots (wave 6: tile 24 x4, writes slot 0 only)

typedef _Float16 h8 __attribute__((ext_vector_type(8)));
union HU { float4 f4; __half hs[8]; };

__device__ __forceinline__ float frcp(float x) { return __builtin_amdgcn_rcpf(x); }
__device__ __forceinline__ float fsig(float x) { return frcp(1.f + __expf(-x)); }
__device__ __forceinline__ float ftanh(float x) { float e = __expf(2.f * x); return 1.f - 2.f * frcp(e + 1.f); }

// LDS-only barrier: drain lgkm (ds ops) but leave global loads/stores in flight.
__device__ __forceinline__ void barrier_lds() {
  asm volatile("s_waitcnt lgkmcnt(0)\n\ts_barrier" ::: "memory");
}

// quad-perm DPP cross-lane (within aligned 4-lane quads): ~VALU-speed, no LDS.
#define QXOR1(d, s) d = __int_as_float(__builtin_amdgcn_mov_dpp(__float_as_int(s), 177, 0xf, 0xf, true)) // [1,0,3,2]
#define QXOR2(d, s) d = __int_as_float(__builtin_amdgcn_mov_dpp(__float_as_int(s),  78, 0xf, 0xf, true)) // [2,3,0,1]
#define QXOR3(d, s) d = __int_as_float(__builtin_amdgcn_mov_dpp(__float_as_int(s),  27, 0xf, 0xf, true)) // [3,2,1,0]

// ---------------------------------------------------------------------------
// Kernel A: compress one-hot x (B,T,400) -> idx2 and q (B,T,200) -> qi.
// ---------------------------------------------------------------------------
__global__ void k_compress(const float* __restrict__ x, const float* __restrict__ q,
                           int* __restrict__ idx2, int* __restrict__ qi) {
  int gid  = blockIdx.x * blockDim.x + threadIdx.x;
  int wave = gid >> 6;
  int lane = threadIdx.x & 63;
  if (wave >= BT) return;

  const float4* xr = (const float4*)(x + (size_t)wave * NCLS);
  int li = -1;
  {
    float4 v = xr[lane];
    if (v.x > 0.5f) li = lane * 4 + 0;
    if (v.y > 0.5f) li = lane * 4 + 1;
    if (v.z > 0.5f) li = lane * 4 + 2;
    if (v.w > 0.5f) li = lane * 4 + 3;
    int ci = 64 + lane;
    if (ci < 100) {
      float4 w = xr[ci];
      if (w.x > 0.5f) li = ci * 4 + 0;
      if (w.y > 0.5f) li = ci * 4 + 1;
      if (w.z > 0.5f) li = ci * 4 + 2;
      if (w.w > 0.5f) li = ci * 4 + 3;
    }
  }
  #pragma unroll
  for (int off = 32; off; off >>= 1) li = max(li, __shfl_xor(li, off));

  const float4* qr = (const float4*)(q + (size_t)wave * TS);
  int qj = -1;
  if (lane < 50) {
    float4 v = qr[lane];
    if (v.x > 0.5f) qj = lane * 4 + 0;
    if (v.y > 0.5f) qj = lane * 4 + 1;
    if (v.z > 0.5f) qj = lane * 4 + 2;
    if (v.w > 0.5f) qj = lane * 4 + 3;
  }
  #pragma unroll
  for (int off = 32; off; off >>= 1) qj = max(qj, __shfl_xor(qj, off));

  if (lane == 0) { idx2[wave] = li; qi[wave] = qj; }
}

// ---------------------------------------------------------------------------
// Kernel A2: count features, fully parallel (one block per b, thread t).
// ccg[b][t] = (log1p(#{t'<=t: idx==s2}), log1p(#{t'<=t: idx==s2+1})),
// s2 = idx[t] & ~1.  Removes the serial scan from the LSTM critical path.
// ---------------------------------------------------------------------------
__global__ void k_counts(const int* __restrict__ idx2, float2* __restrict__ ccg) {
  __shared__ int ids[TT];
  int b = blockIdx.x, tid = threadIdx.x;
  for (int i = tid; i < TT; i += 512) ids[i] = idx2[(size_t)b * TT + i];
  __syncthreads();
  if (tid < TT) {
    int s2 = ids[tid] & ~1;
    int c0 = 0, c1 = 0;
    for (int tp = 0; tp <= tid; ++tp) {
      int v = ids[tp];
      c0 += (v == s2);
      c1 += (v == s2 + 1);
    }
    ccg[(size_t)b * TT + tid] =
        make_float2(__logf(1.f + (float)c0), __logf(1.f + (float)c1));
  }
}

// ---------------------------------------------------------------------------
// Kernel B: precompute permuted tables for the MFMA layout.
// Permutation: orig gate-col j = g*100+u  ->  cp = (u>>2)*16 + (u&3)*4 + g
// (tile n = u>>2 holds units 4n..4n+3; a unit's 4 gates sit in one lane quad).
//  Gq[cls][cp], baseq/c0q/c1q[cp]  (f32)
//  Bfrag[(tile*4+ks)*64 + lane] = float4 of 8 f16: R[k][col(cp)] with
//     k = ks*32 + (lane>>4)*8 + j  (zero-pad k>=100), cp = tile*16+(lane&15)
//  WoT[s][k] = Wo[k][s]
// ---------------------------------------------------------------------------
__global__ void k_precompute(const float* __restrict__ Wx, const float* __restrict__ bx,
                             const float* __restrict__ K, const float* __restrict__ lb,
                             const float* __restrict__ Wo, const float* __restrict__ R,
                             float* __restrict__ Gq, float* __restrict__ baseq,
                             float* __restrict__ c0q, float* __restrict__ c1q,
                             float* __restrict__ WoT, float4* __restrict__ Bfrag) {
  int bid = blockIdx.x, tid = threadIdx.x;
  if (bid < NCLS) {
    if (tid < NG) {
      float acc = 0.0f;
      for (int e = 0; e < TE; ++e) acc = fmaf(Wx[bid * TE + e], K[e * NG + tid], acc);
      int g = tid / 100, u = tid % 100;
      int cp = (u >> 2) * 16 + (u & 3) * 4 + g;
      Gq[bid * NG + cp] = acc;
    }
  } else if (bid == NCLS) {
    if (tid < NG) {
      float acc = lb[tid];
      for (int e = 0; e < TE; ++e) acc = fmaf(bx[e], K[e * NG + tid], acc);
      int g = tid / 100, u = tid % 100;
      int cp = (u >> 2) * 16 + (u & 3) * 4 + g;
      baseq[cp] = acc;
      c0q[cp]   = K[100 * NG + tid] + K[102 * NG + tid];
      c1q[cp]   = K[101 * NG + tid] + K[102 * NG + tid];
    }
  } else {
    int id = (bid - NCLS - 1) * 512 + tid;
    if (id < TS * TH) {
      int s = id / TH, k = id % TH;
      WoT[id] = Wo[k * TS + s];
    } else {
      int id2 = id - TS * TH;
      if (id2 < 6400) {
        int lane = id2 & 63, ks = (id2 >> 6) & 3, tile = id2 >> 8;
        int qq = lane & 15, cgrp = lane >> 4;
        int col = (qq & 3) * 100 + tile * 4 + (qq >> 2);   // orig R column
        HU uu;
        #pragma unroll
        for (int j = 0; j < 8; ++j) {
          int k = ks * 32 + cgrp * 8 + j;
          float v = (k < TH) ? R[k * NG + col] : 0.0f;
          uu.hs[j] = __float2half_rn(v);
        }
        Bfrag[id2] = uu.f4;
      }
    }
  }
}

// ---------------------------------------------------------------------------
// Kernel C: LSTM recurrence on the MATRIX pipe; weights in EXPLICIT AGPRs.
// One block per batch b, 448 threads (7 waves x 4 tile-slots; wave 6 computes
// tile 24 in all 4 slots, writes only slot 0). AGPR map (clobber-reserved,
// outside the allocator — the R2-R8 spill failure mode is impossible):
//   B-frag slot s, k-sub ks: a[16s+4ks : 16s+4ks+3]   (a0..a63, written once)
//   acc slot s:              a[64+4s : 67+4s]          (a64..a79, per step)
//   zero quad:               a[80:83]                  (C of first MFMA)
// A-fragment = h BROADCAST over M (lane reads k-chunk (lane>>4)*8, row-
// independent) so every lane's acc.x = z[its col]. No tied asm operands:
// acc lives in AGPRs, read back with v_accvgpr_read. Gates of one unit sit
// in one lane quad -> 3 quad-perm DPP movs (no LDS shuffle). ONE lgkm-only
// barrier/step; h in 2-row f16 LDS double buffer; G rows + count features
// prefetched depth-2 from global (no serial scan thread — k_counts did it).
// ---------------------------------------------------------------------------
#define AW(N, V) asm volatile("v_accvgpr_write_b32 a" #N ", %0" :: "v"(V) : "a" #N)
#define AW4(N0,N1,N2,N3, F) do { AW(N0,(F).x); AW(N1,(F).y); AW(N2,(F).z); AW(N3,(F).w); } while(0)

#define CLOBS \
  "a0","a1","a2","a3","a4","a5","a6","a7","a8","a9","a10","a11","a12","a13", \
  "a14","a15","a16","a17","a18","a19","a20","a21","a22","a23","a24","a25",   \
  "a26","a27","a28","a29","a30","a31","a32","a33","a34","a35","a36","a37",   \
  "a38","a39","a40","a41","a42","a43","a44","a45","a46","a47","a48","a49",   \
  "a50","a51","a52","a53","a54","a55","a56","a57","a58","a59","a60","a61",   \
  "a62","a63","a64","a65","a66","a67","a68","a69","a70","a71","a72","a73",   \
  "a74","a75","a76","a77","a78","a79","a80","a81","a82","a83"

#define MFMA16(Z0,Z1,Z2,Z3, FA0,FA1,FA2,FA3)                          \
  asm volatile(                                                       \
    "s_nop 1\n\t"                                                     \
    "v_mfma_f32_16x16x32_f16 a[64:67], %4, a[0:3],   a[80:83]\n\t"    \
    "v_mfma_f32_16x16x32_f16 a[68:71], %4, a[16:19], a[80:83]\n\t"    \
    "v_mfma_f32_16x16x32_f16 a[72:75], %4, a[32:35], a[80:83]\n\t"    \
    "v_mfma_f32_16x16x32_f16 a[76:79], %4, a[48:51], a[80:83]\n\t"    \
    "v_mfma_f32_16x16x32_f16 a[64:67], %5, a[4:7],   a[64:67]\n\t"    \
    "v_mfma_f32_16x16x32_f16 a[68:71], %5, a[20:23], a[68:71]\n\t"    \
    "v_mfma_f32_16x16x32_f16 a[72:75], %5, a[36:39], a[72:75]\n\t"    \
    "v_mfma_f32_16x16x32_f16 a[76:79], %5, a[52:55], a[76:79]\n\t"    \
    "v_mfma_f32_16x16x32_f16 a[64:67], %6, a[8:11],  a[64:67]\n\t"    \
    "v_mfma_f32_16x16x32_f16 a[68:71], %6, a[24:27], a[68:71]\n\t"    \
    "v_mfma_f32_16x16x32_f16 a[72:75], %6, a[40:43], a[72:75]\n\t"    \
    "v_mfma_f32_16x16x32_f16 a[76:79], %6, a[56:59], a[76:79]\n\t"    \
    "v_mfma_f32_16x16x32_f16 a[64:67], %7, a[12:15], a[64:67]\n\t"    \
    "v_mfma_f32_16x16x32_f16 a[68:71], %7, a[28:31], a[68:71]\n\t"    \
    "v_mfma_f32_16x16x32_f16 a[72:75], %7, a[44:47], a[72:75]\n\t"    \
    "v_mfma_f32_16x16x32_f16 a[76:79], %7, a[60:63], a[76:79]\n\t"    \
    "s_nop 7\n\ts_nop 7\n\ts_nop 7\n\t"                               \
    "v_accvgpr_read_b32 %0, a64\n\t"                                  \
    "v_accvgpr_read_b32 %1, a68\n\t"                                  \
    "v_accvgpr_read_b32 %2, a72\n\t"                                  \
    "v_accvgpr_read_b32 %3, a76"                                      \
    : "=v"(Z0), "=v"(Z1), "=v"(Z2), "=v"(Z3)                          \
    : "v"(FA0), "v"(FA1), "v"(FA2), "v"(FA3)                          \
    : CLOBS)

__global__ void __attribute__((amdgpu_flat_work_group_size(BLK, BLK)))
k_lstm(const int* __restrict__ idx2, const float* __restrict__ Gq,
       const float* __restrict__ baseq, const float* __restrict__ c0q,
       const float* __restrict__ c1q, const float4* __restrict__ Bfrag,
       const float2* __restrict__ ccg, float* __restrict__ h_seq) {
  __shared__ __align__(16) __half hbuf[2][128];   // padded h rows (k>=100 stay 0)
  __shared__ int idx_ls[TT];

  int b = blockIdx.x, tid = threadIdx.x;
  int w = tid >> 6, lane = tid & 63;
  int q = lane & 15, g3 = q & 3, cg = lane >> 4;

  for (int i = tid; i < TT; i += BLK) idx_ls[i] = idx2[(size_t)b * TT + i];
  if (tid < 128) { hbuf[0][tid] = __float2half(0.f); hbuf[1][tid] = __float2half(0.f); }

  int tS0 = (w < 6) ? 4 * w     : 24;
  int tS1 = (w < 6) ? 4 * w + 1 : 24;
  int tS2 = (w < 6) ? 4 * w + 2 : 24;
  int tS3 = (w < 6) ? 4 * w + 3 : 24;
  int colp0 = tS0 * 16 + q, colp1 = tS1 * 16 + q;
  int colp2 = tS2 * 16 + q, colp3 = tS3 * 16 + q;
  float base0 = baseq[colp0], c00 = c0q[colp0], c10 = c1q[colp0];
  float base1 = baseq[colp1], c01 = c0q[colp1], c11 = c1q[colp1];
  float base2 = baseq[colp2], c02 = c0q[colp2], c12 = c1q[colp2];
  float base3 = baseq[colp3], c03 = c0q[colp3], c13 = c1q[colp3];
  int u0 = tS0 * 4 + (lane >> 2), u1 = tS1 * 4 + (lane >> 2);
  int u2 = tS2 * 4 + (lane >> 2), u3 = tS3 * 4 + (lane >> 2);
  bool wr = (lane < 16) && ((lane & 3) == 0);      // g==0 lanes, one per quad

  // ---- load B fragments into AGPRs (once) ----
  {
    float4 f;
    f = Bfrag[(tS0 * 4 + 0) * 64 + lane]; AW4(0,1,2,3, f);
    f = Bfrag[(tS0 * 4 + 1) * 64 + lane]; AW4(4,5,6,7, f);
    f = Bfrag[(tS0 * 4 + 2) * 64 + lane]; AW4(8,9,10,11, f);
    f = Bfrag[(tS0 * 4 + 3) * 64 + lane]; AW4(12,13,14,15, f);
    f = Bfrag[(tS1 * 4 + 0) * 64 + lane]; AW4(16,17,18,19, f);
    f = Bfrag[(tS1 * 4 + 1) * 64 + lane]; AW4(20,21,22,23, f);
    f = Bfrag[(tS1 * 4 + 2) * 64 + lane]; AW4(24,25,26,27, f);
    f = Bfrag[(tS1 * 4 + 3) * 64 + lane]; AW4(28,29,30,31, f);
    f = Bfrag[(tS2 * 4 + 0) * 64 + lane]; AW4(32,33,34,35, f);
    f = Bfrag[(tS2 * 4 + 1) * 64 + lane]; AW4(36,37,38,39, f);
    f = Bfrag[(tS2 * 4 + 2) * 64 + lane]; AW4(40,41,42,43, f);
    f = Bfrag[(tS2 * 4 + 3) * 64 + lane]; AW4(44,45,46,47, f);
    f = Bfrag[(tS3 * 4 + 0) * 64 + lane]; AW4(48,49,50,51, f);
    f = Bfrag[(tS3 * 4 + 1) * 64 + lane]; AW4(52,53,54,55, f);
    f = Bfrag[(tS3 * 4 + 2) * 64 + lane]; AW4(56,57,58,59, f);
    f = Bfrag[(tS3 * 4 + 3) * 64 + lane]; AW4(60,61,62,63, f);
    float zf = 0.0f;
    AW(80, zf); AW(81, zf); AW(82, zf); AW(83, zf);
  }
  // full-a clobber fence: nothing compiler-managed may live in a0..a83 past here
  asm volatile("" ::: CLOBS);

  float c_reg0 = 0.f, c_reg1 = 0.f, c_reg2 = 0.f, c_reg3 = 0.f;
  __syncthreads();               // idx_ls, hbuf visible

  const float2* ccg_b = ccg + (size_t)b * TT;
  // prefetch depth 2: G rows + count features
  const float* Gr0 = Gq + (size_t)idx_ls[0] * NG;
  const float* Gr1 = Gq + (size_t)idx_ls[1] * NG;
  float gA0 = Gr0[colp0], gA1 = Gr0[colp1], gA2 = Gr0[colp2], gA3 = Gr0[colp3];
  float gB0 = Gr1[colp0], gB1 = Gr1[colp1], gB2 = Gr1[colp2], gB3 = Gr1[colp3];
  float2 ccA = ccg_b[0], ccB = ccg_b[1];

  float* hout = h_seq + (size_t)b * TT * TH;

  #define TILE_Z(ZV, GV, BASE, C0, C1, CREG, HN)                               \
  { float z = (ZV) + (GV) + (BASE) + cc.x * (C0) + cc.y * (C1);                \
    float arg = (g3 == 2) ? (z + z) : (-z);                                    \
    float E = __expf(arg);                                                     \
    float r = frcp(1.f + E);                                                   \
    float act = (g3 == 2) ? fmaf(-2.f, r, 1.f) : r;                            \
    float x1, x2, x3;                                                          \
    QXOR1(x1, act); QXOR2(x2, act); QXOR3(x3, act);                            \
    (CREG) = fmaf(x1, (CREG), act * x2);  /* g0 lanes: ai=act af=x1 ag=x2 */   \
    (HN) = x3 * ftanh(CREG); }

  #define STEP(T_, PAR, G0, G1, G2, G3, CCV)                                   \
  { const int t_ = (T_);                                                       \
    barrier_lds();               /* h(t-1) visible; VMEM stays in flight */    \
    const h8* hrow = (const h8*)(&hbuf[(PAR) ^ 1][0]);                         \
    h8 fa0 = hrow[cg], fa1 = hrow[4 + cg], fa2 = hrow[8 + cg], fa3 = hrow[12 + cg]; \
    float z0, z1, z2, z3;                                                      \
    MFMA16(z0, z1, z2, z3, fa0, fa1, fa2, fa3);                                \
    float2 cc = (CCV);                                                         \
    int tnx = (t_ + 2 < TT) ? t_ + 2 : TT - 1;                                 \
    const float* Gn = Gq + (size_t)idx_ls[tnx] * NG;                           \
    float hn0, hn1, hn2, hn3;                                                  \
    TILE_Z(z0, (G0), base0, c00, c10, c_reg0, hn0); (G0) = Gn[colp0];          \
    TILE_Z(z1, (G1), base1, c01, c11, c_reg1, hn1); (G1) = Gn[colp1];          \
    TILE_Z(z2, (G2), base2, c02, c12, c_reg2, hn2); (G2) = Gn[colp2];          \
    TILE_Z(z3, (G3), base3, c03, c13, c_reg3, hn3); (G3) = Gn[colp3];          \
    (CCV) = ccg_b[tnx];                                                        \
    if (wr) {                                                                  \
      hbuf[PAR][u0] = __float2half_rn(hn0);                                    \
      hout[(size_t)t_ * TH + u0] = hn0;          /* un-drained store */        \
      if (w != 6) {                                                            \
        hbuf[PAR][u1] = __float2half_rn(hn1);                                  \
        hout[(size_t)t_ * TH + u1] = hn1;                                      \
        hbuf[PAR][u2] = __float2half_rn(hn2);                                  \
        hout[(size_t)t_ * TH + u2] = hn2;                                      \
        hbuf[PAR][u3] = __float2half_rn(hn3);                                  \
        hout[(size_t)t_ * TH + u3] = hn3;                                      \
      }                                                                        \
    }                                                                          \
  }

  for (int t2 = 0; t2 < TT; t2 += 2) {
    STEP(t2, 0, gA0, gA1, gA2, gA3, ccA);      // even t: read hbuf[1], write hbuf[0]
    STEP(t2 + 1, 1, gB0, gB1, gB2, gB3, ccB);  // odd  t: read hbuf[0], write hbuf[1]
  }
  #undef STEP
  #undef TILE_Z
}

// ---------------------------------------------------------------------------
// Kernel D: out[b,t] = sigmoid( h_seq[b,t] . WoT[qi[b,t]] + bo[qi] )
// ---------------------------------------------------------------------------
__global__ void k_out(const float* __restrict__ h_seq, const float* __restrict__ WoT,
                      const float* __restrict__ bo, const int* __restrict__ qi,
                      float* __restrict__ out) {
  int gid  = blockIdx.x * blockDim.x + threadIdx.x;
  int wave = gid >> 6;
  int lane = threadIdx.x & 63;
  if (wave >= BT) return;
  int s = qi[wave];
  const float4* h4 = (const float4*)(h_seq + (size_t)wave * TH);
  const float4* w4 = (const float4*)(WoT + (size_t)s * TH);
  float acc = 0.0f;
  if (lane < TH / 4) {
    float4 h = h4[lane];
    float4 w = w4[lane];
    acc = h.x * w.x + h.y * w.y + h.z * w.z + h.w * w.w;
  }
  #pragma unroll
  for (int off = 32; off; off >>= 1) acc += __shfl_xor(acc, off);
  if (lane == 0) out[wave] = fsig(acc + bo[s]);
}

// ---------------------------------------------------------------------------
extern "C" void kernel_launch(void* const* d_in, const int* in_sizes, int n_in,
                              void* d_out, int out_size, void* d_ws, size_t ws_size,
                              hipStream_t stream) {
  const float* x    = (const float*)d_in[0];
  // d_in[1] = delta (unused by the reference)
  const float* q    = (const float*)d_in[2];
  const float* Wx   = (const float*)d_in[3];
  const float* bx   = (const float*)d_in[4];
  const float* K    = (const float*)d_in[5];   // lstm_k (103,400)
  const float* R    = (const float*)d_in[6];   // lstm_rk (100,400)
  const float* lb   = (const float*)d_in[7];   // lstm_b (400)
  const float* Wo   = (const float*)d_in[8];   // (100,200)
  const float* bo   = (const float*)d_in[9];   // (200)
  float* out = (float*)d_out;

  // workspace layout (floats)
  float* ws = (float*)d_ws;
  float*  Gq     = ws;                      // 160000
  float*  baseq  = ws + 160000;             // 400
  float*  c0q    = ws + 160400;             // 400
  float*  c1q    = ws + 160800;             // 400
  float*  WoT    = ws + 161200;             // 20000
  float4* Bfrag  = (float4*)(ws + 181200);  // 6400 float4 = 25600 floats
  int*    idx2   = (int*)(ws + 206800);     // 64000
  int*    qi     = (int*)(ws + 270800);     // 64000
  float2* ccg    = (float2*)(ws + 334800);  // 64000 float2 = 128000 floats
  float*  h_seq  = ws + 462800;             // 6,400,000
  // total: 6,862,800 floats = 27.5 MB

  // A: compress one-hots
  k_compress<<<BT / 4, 256, 0, stream>>>(x, q, idx2, qi);

  // A2: parallel count features (replaces the in-loop serial scan)
  k_counts<<<TB, 512, 0, stream>>>(idx2, ccg);

  // B: precompute permuted tables + MFMA B-fragments
  int tail_blocks = (TS * TH + 6400 + 511) / 512;        // 52
  k_precompute<<<NCLS + 1 + tail_blocks, 512, 0, stream>>>(Wx, bx, K, lb, Wo, R,
                                                           Gq, baseq, c0q, c1q, WoT, Bfrag);

  // C: sequential LSTM, one block per batch element, MFMA recurrence
  k_lstm<<<TB, BLK, 0, stream>>>(idx2, Gq, baseq, c0q, c1q, Bfrag, ccg, h_seq);

  // D: gather + dot + sigmoid
  k_out<<<BT / 4, 256, 0, stream>>>(h_seq, WoT, bo, qi, out);
}

// Round 11
// 304.139 us; speedup vs baseline: 1.7900x; 1.4782x over previous
//
#include <hip/hip_runtime.h>
#include <hip/hip_bf16.h>
#include <hip/hip_fp16.h>

// Problem constants
#define TB 128
#define TT 500
#define TS 200
#define TE 100
#define TH 100
#define NCLS 400              // 2*S  (one-hot width of x)
#define NG   400              // 4*H  (gate width)
#define BT   (TB*TT)          // 64000 (b,t) pairs
#define BLK  448              // 7 waves x 4 tile-slots (wave 6: tile 24 x4, rg0 writes)

typedef _Float16 h8 __attribute__((ext_vector_type(8)));
union HU { float4 f4; __half hs[8]; };

__device__ __forceinline__ float frcp(float x) { return __builtin_amdgcn_rcpf(x); }
__device__ __forceinline__ float fsig(float x) { return frcp(1.f + __expf(-x)); }
__device__ __forceinline__ float ftanh(float x) { float e = __expf(2.f * x); return 1.f - 2.f * frcp(e + 1.f); }

// LDS-only barrier: drain lgkm (ds ops) but leave global loads/stores in flight.
__device__ __forceinline__ void barrier_lds() {
  asm volatile("s_waitcnt lgkmcnt(0)\n\ts_barrier" ::: "memory");
}

// quad-perm DPP cross-lane (within aligned 4-lane quads): ~VALU-speed, no LDS.
#define QXOR1(d, s) d = __int_as_float(__builtin_amdgcn_mov_dpp(__float_as_int(s), 177, 0xf, 0xf, true)) // [1,0,3,2]
#define QXOR2(d, s) d = __int_as_float(__builtin_amdgcn_mov_dpp(__float_as_int(s),  78, 0xf, 0xf, true)) // [2,3,0,1]
#define QXOR3(d, s) d = __int_as_float(__builtin_amdgcn_mov_dpp(__float_as_int(s),  27, 0xf, 0xf, true)) // [3,2,1,0]

// ---------------------------------------------------------------------------
// Kernel A: compress one-hot x (B,T,400) -> idx2 and q (B,T,200) -> qi.
// ---------------------------------------------------------------------------
__global__ void k_compress(const float* __restrict__ x, const float* __restrict__ q,
                           int* __restrict__ idx2, int* __restrict__ qi) {
  int gid  = blockIdx.x * blockDim.x + threadIdx.x;
  int wave = gid >> 6;
  int lane = threadIdx.x & 63;
  if (wave >= BT) return;

  const float4* xr = (const float4*)(x + (size_t)wave * NCLS);
  int li = -1;
  {
    float4 v = xr[lane];
    if (v.x > 0.5f) li = lane * 4 + 0;
    if (v.y > 0.5f) li = lane * 4 + 1;
    if (v.z > 0.5f) li = lane * 4 + 2;
    if (v.w > 0.5f) li = lane * 4 + 3;
    int ci = 64 + lane;
    if (ci < 100) {
      float4 w = xr[ci];
      if (w.x > 0.5f) li = ci * 4 + 0;
      if (w.y > 0.5f) li = ci * 4 + 1;
      if (w.z > 0.5f) li = ci * 4 + 2;
      if (w.w > 0.5f) li = ci * 4 + 3;
    }
  }
  #pragma unroll
  for (int off = 32; off; off >>= 1) li = max(li, __shfl_xor(li, off));

  const float4* qr = (const float4*)(q + (size_t)wave * TS);
  int qj = -1;
  if (lane < 50) {
    float4 v = qr[lane];
    if (v.x > 0.5f) qj = lane * 4 + 0;
    if (v.y > 0.5f) qj = lane * 4 + 1;
    if (v.z > 0.5f) qj = lane * 4 + 2;
    if (v.w > 0.5f) qj = lane * 4 + 3;
  }
  #pragma unroll
  for (int off = 32; off; off >>= 1) qj = max(qj, __shfl_xor(qj, off));

  if (lane == 0) { idx2[wave] = li; qi[wave] = qj; }
}

// ---------------------------------------------------------------------------
// Kernel A2: count features, fully parallel (one block per b, thread t).
// ---------------------------------------------------------------------------
__global__ void k_counts(const int* __restrict__ idx2, float2* __restrict__ ccg) {
  __shared__ int ids[TT];
  int b = blockIdx.x, tid = threadIdx.x;
  for (int i = tid; i < TT; i += 512) ids[i] = idx2[(size_t)b * TT + i];
  __syncthreads();
  if (tid < TT) {
    int s2 = ids[tid] & ~1;
    int c0 = 0, c1 = 0;
    for (int tp = 0; tp <= tid; ++tp) {
      int v = ids[tp];
      c0 += (v == s2);
      c1 += (v == s2 + 1);
    }
    ccg[(size_t)b * TT + tid] =
        make_float2(__logf(1.f + (float)c0), __logf(1.f + (float)c1));
  }
}

// ---------------------------------------------------------------------------
// Kernel B: precompute permuted tables for the MFMA layout.
// Permutation: orig gate-col j = g*100+u  ->  cp = (u>>2)*16 + (u&3)*4 + g
//  Gq[cls][cp], baseq/c0q/c1q[cp]  (f32)
//  Bfrag[(tile*4+ks)*64 + lane] = float4 of 8 f16: R[k][col(cp)] with
//     k = ks*32 + (lane>>4)*8 + j  (zero-pad k>=100), cp = tile*16+(lane&15)
//  WoT[s][k] = Wo[k][s]
// ---------------------------------------------------------------------------
__global__ void k_precompute(const float* __restrict__ Wx, const float* __restrict__ bx,
                             const float* __restrict__ K, const float* __restrict__ lb,
                             const float* __restrict__ Wo, const float* __restrict__ R,
                             float* __restrict__ Gq, float* __restrict__ baseq,
                             float* __restrict__ c0q, float* __restrict__ c1q,
                             float* __restrict__ WoT, float4* __restrict__ Bfrag) {
  int bid = blockIdx.x, tid = threadIdx.x;
  if (bid < NCLS) {
    if (tid < NG) {
      float acc = 0.0f;
      for (int e = 0; e < TE; ++e) acc = fmaf(Wx[bid * TE + e], K[e * NG + tid], acc);
      int g = tid / 100, u = tid % 100;
      int cp = (u >> 2) * 16 + (u & 3) * 4 + g;
      Gq[bid * NG + cp] = acc;
    }
  } else if (bid == NCLS) {
    if (tid < NG) {
      float acc = lb[tid];
      for (int e = 0; e < TE; ++e) acc = fmaf(bx[e], K[e * NG + tid], acc);
      int g = tid / 100, u = tid % 100;
      int cp = (u >> 2) * 16 + (u & 3) * 4 + g;
      baseq[cp] = acc;
      c0q[cp]   = K[100 * NG + tid] + K[102 * NG + tid];
      c1q[cp]   = K[101 * NG + tid] + K[102 * NG + tid];
    }
  } else {
    int id = (bid - NCLS - 1) * 512 + tid;
    if (id < TS * TH) {
      int s = id / TH, k = id % TH;
      WoT[id] = Wo[k * TS + s];
    } else {
      int id2 = id - TS * TH;
      if (id2 < 6400) {
        int lane = id2 & 63, ks = (id2 >> 6) & 3, tile = id2 >> 8;
        int qq = lane & 15, cgrp = lane >> 4;
        int col = (qq & 3) * 100 + tile * 4 + (qq >> 2);   // orig R column
        HU uu;
        #pragma unroll
        for (int j = 0; j < 8; ++j) {
          int k = ks * 32 + cgrp * 8 + j;
          float v = (k < TH) ? R[k * NG + col] : 0.0f;
          uu.hs[j] = __float2half_rn(v);
        }
        Bfrag[id2] = uu.f4;
      }
    }
  }
}

// ---------------------------------------------------------------------------
// Kernel C: LSTM recurrence on the MATRIX pipe; weights in EXPLICIT AGPRs.
// R10 wiring (passed) + "slot = row-group" mapping: all 16 C-rows of each
// slot are identical (broadcast-A), so row-group cg handles ONLY slot cg's
// activation: select z[cg] by 3 cndmask -> ONE TILE_Z per lane (was 4).
// Cascades: G gather per lane col = 64w+lane -> ONE coalesced 256B load per
// wave; base/c0/c1 one scalar each; ONE ds_write_b16 per wave (16 writer
// lanes g3==0, unit u=16w+4cg+qd, masked u<100 so hbuf zero-padding stays
// intact — wave 6's duplicate row-groups are exactly the masked ones).
// AGPR map unchanged: B-frags a0..a63 (written once), acc a64..a79,
// zero quad a80..a83, all clobber-reserved (allocator can't spill them).
// ONE lgkm-only barrier/step; h in 2-row f16 LDS dbuf; G/ccg prefetch depth-2.
// ---------------------------------------------------------------------------
#define AW(N, V) asm volatile("v_accvgpr_write_b32 a" #N ", %0" :: "v"(V) : "a" #N)
#define AW4(N0,N1,N2,N3, F) do { AW(N0,(F).x); AW(N1,(F).y); AW(N2,(F).z); AW(N3,(F).w); } while(0)

#define CLOBS \
  "a0","a1","a2","a3","a4","a5","a6","a7","a8","a9","a10","a11","a12","a13", \
  "a14","a15","a16","a17","a18","a19","a20","a21","a22","a23","a24","a25",   \
  "a26","a27","a28","a29","a30","a31","a32","a33","a34","a35","a36","a37",   \
  "a38","a39","a40","a41","a42","a43","a44","a45","a46","a47","a48","a49",   \
  "a50","a51","a52","a53","a54","a55","a56","a57","a58","a59","a60","a61",   \
  "a62","a63","a64","a65","a66","a67","a68","a69","a70","a71","a72","a73",   \
  "a74","a75","a76","a77","a78","a79","a80","a81","a82","a83"

#define MFMA16(Z0,Z1,Z2,Z3, FA0,FA1,FA2,FA3)                          \
  asm volatile(                                                       \
    "s_nop 1\n\t"                                                     \
    "v_mfma_f32_16x16x32_f16 a[64:67], %4, a[0:3],   a[80:83]\n\t"    \
    "v_mfma_f32_16x16x32_f16 a[68:71], %4, a[16:19], a[80:83]\n\t"    \
    "v_mfma_f32_16x16x32_f16 a[72:75], %4, a[32:35], a[80:83]\n\t"    \
    "v_mfma_f32_16x16x32_f16 a[76:79], %4, a[48:51], a[80:83]\n\t"    \
    "v_mfma_f32_16x16x32_f16 a[64:67], %5, a[4:7],   a[64:67]\n\t"    \
    "v_mfma_f32_16x16x32_f16 a[68:71], %5, a[20:23], a[68:71]\n\t"    \
    "v_mfma_f32_16x16x32_f16 a[72:75], %5, a[36:39], a[72:75]\n\t"    \
    "v_mfma_f32_16x16x32_f16 a[76:79], %5, a[52:55], a[76:79]\n\t"    \
    "v_mfma_f32_16x16x32_f16 a[64:67], %6, a[8:11],  a[64:67]\n\t"    \
    "v_mfma_f32_16x16x32_f16 a[68:71], %6, a[24:27], a[68:71]\n\t"    \
    "v_mfma_f32_16x16x32_f16 a[72:75], %6, a[40:43], a[72:75]\n\t"    \
    "v_mfma_f32_16x16x32_f16 a[76:79], %6, a[56:59], a[76:79]\n\t"    \
    "v_mfma_f32_16x16x32_f16 a[64:67], %7, a[12:15], a[64:67]\n\t"    \
    "v_mfma_f32_16x16x32_f16 a[68:71], %7, a[28:31], a[68:71]\n\t"    \
    "v_mfma_f32_16x16x32_f16 a[72:75], %7, a[44:47], a[72:75]\n\t"    \
    "v_mfma_f32_16x16x32_f16 a[76:79], %7, a[60:63], a[76:79]\n\t"    \
    "s_nop 7\n\ts_nop 7\n\ts_nop 7\n\t"                               \
    "v_accvgpr_read_b32 %0, a64\n\t"                                  \
    "v_accvgpr_read_b32 %1, a68\n\t"                                  \
    "v_accvgpr_read_b32 %2, a72\n\t"                                  \
    "v_accvgpr_read_b32 %3, a76"                                      \
    : "=v"(Z0), "=v"(Z1), "=v"(Z2), "=v"(Z3)                          \
    : "v"(FA0), "v"(FA1), "v"(FA2), "v"(FA3)                          \
    : CLOBS)

__global__ void __attribute__((amdgpu_flat_work_group_size(BLK, BLK)))
k_lstm(const int* __restrict__ idx2, const float* __restrict__ Gq,
       const float* __restrict__ baseq, const float* __restrict__ c0q,
       const float* __restrict__ c1q, const float4* __restrict__ Bfrag,
       const float2* __restrict__ ccg, float* __restrict__ h_seq) {
  __shared__ __align__(16) __half hbuf[2][128];   // padded h rows (k>=100 stay 0)
  __shared__ int idx_ls[TT];

  int b = blockIdx.x, tid = threadIdx.x;
  int w = tid >> 6, lane = tid & 63;
  int g3 = lane & 3, cg = lane >> 4, qd = (lane >> 2) & 3;

  for (int i = tid; i < TT; i += BLK) idx_ls[i] = idx2[(size_t)b * TT + i];
  if (tid < 128) { hbuf[0][tid] = __float2half(0.f); hbuf[1][tid] = __float2half(0.f); }

  int tS0 = (w < 6) ? 4 * w     : 24;
  int tS1 = (w < 6) ? 4 * w + 1 : 24;
  int tS2 = (w < 6) ? 4 * w + 2 : 24;
  int tS3 = (w < 6) ? 4 * w + 3 : 24;

  // per-lane single column (slot = row-group cg): col = tS_cg*16 + (lane&15)
  // for the uniform-tile waves (w<6) this is exactly 64w + lane (coalesced)
  int gcol = (w < 6) ? (64 * w + lane)
                     : (24 * 16 + (lane & 15));   // wave 6: all rgs tile 24
  float basej = baseq[gcol], c0j = c0q[gcol], c1j = c1q[gcol];
  int u_wr = 16 * w + 4 * cg + qd;                // writer's unit (w<6); w6: rg0 only
  bool wr = (g3 == 0) && (((w < 6) ? u_wr : (96 + qd)) < TH) && !(w == 6 && cg != 0);
  int u_fin = (w < 6) ? u_wr : (96 + qd);

  // ---- load B fragments into AGPRs (once) ----
  {
    float4 f;
    f = Bfrag[(tS0 * 4 + 0) * 64 + lane]; AW4(0,1,2,3, f);
    f = Bfrag[(tS0 * 4 + 1) * 64 + lane]; AW4(4,5,6,7, f);
    f = Bfrag[(tS0 * 4 + 2) * 64 + lane]; AW4(8,9,10,11, f);
    f = Bfrag[(tS0 * 4 + 3) * 64 + lane]; AW4(12,13,14,15, f);
    f = Bfrag[(tS1 * 4 + 0) * 64 + lane]; AW4(16,17,18,19, f);
    f = Bfrag[(tS1 * 4 + 1) * 64 + lane]; AW4(20,21,22,23, f);
    f = Bfrag[(tS1 * 4 + 2) * 64 + lane]; AW4(24,25,26,27, f);
    f = Bfrag[(tS1 * 4 + 3) * 64 + lane]; AW4(28,29,30,31, f);
    f = Bfrag[(tS2 * 4 + 0) * 64 + lane]; AW4(32,33,34,35, f);
    f = Bfrag[(tS2 * 4 + 1) * 64 + lane]; AW4(36,37,38,39, f);
    f = Bfrag[(tS2 * 4 + 2) * 64 + lane]; AW4(40,41,42,43, f);
    f = Bfrag[(tS2 * 4 + 3) * 64 + lane]; AW4(44,45,46,47, f);
    f = Bfrag[(tS3 * 4 + 0) * 64 + lane]; AW4(48,49,50,51, f);
    f = Bfrag[(tS3 * 4 + 1) * 64 + lane]; AW4(52,53,54,55, f);
    f = Bfrag[(tS3 * 4 + 2) * 64 + lane]; AW4(56,57,58,59, f);
    f = Bfrag[(tS3 * 4 + 3) * 64 + lane]; AW4(60,61,62,63, f);
    float zf = 0.0f;
    AW(80, zf); AW(81, zf); AW(82, zf); AW(83, zf);
  }
  asm volatile("" ::: CLOBS);    // a0..a83 reserved for the whole kernel

  float c_reg = 0.f;
  __syncthreads();               // idx_ls, hbuf visible

  const float2* ccg_b = ccg + (size_t)b * TT;
  float gA = Gq[(size_t)idx_ls[0] * NG + gcol];
  float gB = Gq[(size_t)idx_ls[1] * NG + gcol];
  float2 ccA = ccg_b[0], ccB = ccg_b[1];

  float* hout = h_seq + (size_t)b * TT * TH;

  #define STEP(T_, PAR, GV, CCV)                                               \
  { const int t_ = (T_);                                                       \
    barrier_lds();               /* h(t-1) visible; VMEM stays in flight */    \
    const h8* hrow = (const h8*)(&hbuf[(PAR) ^ 1][0]);                         \
    h8 fa0 = hrow[cg], fa1 = hrow[4 + cg], fa2 = hrow[8 + cg], fa3 = hrow[12 + cg]; \
    float z0, z1, z2, z3;                                                      \
    MFMA16(z0, z1, z2, z3, fa0, fa1, fa2, fa3);                                \
    float zlo = (cg & 1) ? z1 : z0;                                            \
    float zhi = (cg & 1) ? z3 : z2;                                            \
    float zsel = (cg & 2) ? zhi : zlo;                                         \
    float2 cc = (CCV);                                                         \
    int tnx = (t_ + 2 < TT) ? t_ + 2 : TT - 1;                                 \
    float z = zsel + (GV) + basej + cc.x * c0j + cc.y * c1j;                   \
    (GV) = Gq[(size_t)idx_ls[tnx] * NG + gcol];   /* coalesced refill */       \
    (CCV) = ccg_b[tnx];                                                        \
    float arg = (g3 == 2) ? (z + z) : (-z);                                    \
    float E = __expf(arg);                                                     \
    float r = frcp(1.f + E);                                                   \
    float act = (g3 == 2) ? fmaf(-2.f, r, 1.f) : r;                            \
    float x1, x2, x3;                                                          \
    QXOR1(x1, act); QXOR2(x2, act); QXOR3(x3, act);                            \
    c_reg = fmaf(x1, c_reg, act * x2);   /* valid on g3==0 lanes */            \
    float hn = x3 * ftanh(c_reg);                                              \
    if (wr) {                                                                  \
      hbuf[PAR][u_fin] = __float2half_rn(hn);     /* ONE ds_write per wave */  \
      hout[(size_t)t_ * TH + u_fin] = hn;         /* un-drained store */       \
    }                                                                          \
  }

  for (int t2 = 0; t2 < TT; t2 += 2) {
    STEP(t2, 0, gA, ccA);      // even t: read hbuf[1], write hbuf[0]
    STEP(t2 + 1, 1, gB, ccB);  // odd  t: read hbuf[0], write hbuf[1]
  }
  #undef STEP
}

// ---------------------------------------------------------------------------
// Kernel D: out[b,t] = sigmoid( h_seq[b,t] . WoT[qi[b,t]] + bo[qi] )
// ---------------------------------------------------------------------------
__global__ void k_out(const float* __restrict__ h_seq, const float* __restrict__ WoT,
                      const float* __restrict__ bo, const int* __restrict__ qi,
                      float* __restrict__ out) {
  int gid  = blockIdx.x * blockDim.x + threadIdx.x;
  int wave = gid >> 6;
  int lane = threadIdx.x & 63;
  if (wave >= BT) return;
  int s = qi[wave];
  const float4* h4 = (const float4*)(h_seq + (size_t)wave * TH);
  const float4* w4 = (const float4*)(WoT + (size_t)s * TH);
  float acc = 0.0f;
  if (lane < TH / 4) {
    float4 h = h4[lane];
    float4 w = w4[lane];
    acc = h.x * w.x + h.y * w.y + h.z * w.z + h.w * w.w;
  }
  #pragma unroll
  for (int off = 32; off; off >>= 1) acc += __shfl_xor(acc, off);
  if (lane == 0) out[wave] = fsig(acc + bo[s]);
}

// ---------------------------------------------------------------------------
extern "C" void kernel_launch(void* const* d_in, const int* in_sizes, int n_in,
                              void* d_out, int out_size, void* d_ws, size_t ws_size,
                              hipStream_t stream) {
  const float* x    = (const float*)d_in[0];
  // d_in[1] = delta (unused by the reference)
  const float* q    = (const float*)d_in[2];
  const float* Wx   = (const float*)d_in[3];
  const float* bx   = (const float*)d_in[4];
  const float* K    = (const float*)d_in[5];   // lstm_k (103,400)
  const float* R    = (const float*)d_in[6];   // lstm_rk (100,400)
  const float* lb   = (const float*)d_in[7];   // lstm_b (400)
  const float* Wo   = (const float*)d_in[8];   // (100,200)
  const float* bo   = (const float*)d_in[9];   // (200)
  float* out = (float*)d_out;

  // workspace layout (floats)
  float* ws = (float*)d_ws;
  float*  Gq     = ws;                      // 160000
  float*  baseq  = ws + 160000;             // 400
  float*  c0q    = ws + 160400;             // 400
  float*  c1q    = ws + 160800;             // 400
  float*  WoT    = ws + 161200;             // 20000
  float4* Bfrag  = (float4*)(ws + 181200);  // 6400 float4 = 25600 floats
  int*    idx2   = (int*)(ws + 206800);     // 64000
  int*    qi     = (int*)(ws + 270800);     // 64000
  float2* ccg    = (float2*)(ws + 334800);  // 64000 float2 = 128000 floats
  float*  h_seq  = ws + 462800;             // 6,400,000
  // total: 6,862,800 floats = 27.5 MB

  // A: compress one-hots
  k_compress<<<BT / 4, 256, 0, stream>>>(x, q, idx2, qi);

  // A2: parallel count features
  k_counts<<<TB, 512, 0, stream>>>(idx2, ccg);

  // B: precompute permuted tables + MFMA B-fragments
  int tail_blocks = (TS * TH + 6400 + 511) / 512;        // 52
  k_precompute<<<NCLS + 1 + tail_blocks, 512, 0, stream>>>(Wx, bx, K, lb, Wo, R,
                                                           Gq, baseq, c0q, c1q, WoT, Bfrag);

  // C: sequential LSTM, one block per batch element, MFMA recurrence
  k_lstm<<<TB, BLK, 0, stream>>>(idx2, Gq, baseq, c0q, c1q, Bfrag, ccg, h_seq);

  // D: gather + dot + sigmoid
  k_out<<<BT / 4, 256, 0, stream>>>(h_seq, WoT, bo, qi, out);
}